// Round 3
// baseline (927.042 us; speedup 1.0000x reference)
//
#include <hip/hip_runtime.h>

#define EMB 128
#define NBMAX 2048     // max buckets (etp: 1563)
#define BSHIFT 6       // 64 rows per bucket
#define TILE 8192      // entries per k_bin tile
#define BINBLK 1024    // k_bin threads (16 waves -> 4 waves/SIMD at 1 block/CU)
#define CHUNK 4096     // entries per k_bspmm LDS chunk

typedef float v4f __attribute__((ext_vector_type(4)));
typedef short v8s __attribute__((ext_vector_type(8)));
typedef unsigned int u32;

__device__ inline float bf_lo(u32 u) { return __builtin_bit_cast(float, u << 16); }
__device__ inline float bf_hi(u32 u) { return __builtin_bit_cast(float, u & 0xffff0000u); }
__device__ inline float bfv(u32 e) { return __builtin_bit_cast(float, (e & 0x7FFFu) << 16); }
__device__ inline unsigned short f2bf(float x) {
    u32 u = __builtin_bit_cast(u32, x);
    return (unsigned short)((u + 0x7fffu + ((u >> 16) & 1u)) >> 16);   // RNE
}

// async global -> LDS, 4B/lane: HW dest = uniform lds base + 4*lane, src per-lane.
__device__ __forceinline__ void gl_lds(const void* g, void* l) {
    __builtin_amdgcn_global_load_lds(
        (const __attribute__((address_space(1))) u32*)g,
        (__attribute__((address_space(3))) u32*)l, 4, 0, 0);
}

// ---------------- A: bucket counts (LDS-privatized) ----------------
__global__ __launch_bounds__(256) void k_bcount(const int* __restrict__ rows, int n,
                                                int* __restrict__ cnt) {
    __shared__ int lh[NBMAX];
    for (int j = threadIdx.x; j < NBMAX; j += 256) lh[j] = 0;
    __syncthreads();
    for (int i = blockIdx.x * 256 + threadIdx.x; i < n; i += gridDim.x * 256)
        atomicAdd(&lh[rows[i] >> BSHIFT], 1);
    __syncthreads();
    for (int j = threadIdx.x; j < NBMAX; j += 256)
        if (lh[j]) atomicAdd(&cnt[j], lh[j]);
}

// ---------------- B: exclusive scan of NBMAX bucket counts -> bstart, bcur ----------------
__global__ __launch_bounds__(256) void k_bscan(const int* __restrict__ cnt,
                                               int* __restrict__ bstart, int* __restrict__ bcur) {
    __shared__ int wsum[4];
    __shared__ int wpre[4];
    int tid = threadIdx.x, lane = tid & 63, wv = tid >> 6;
    int v[8];
    int s = 0;
    #pragma unroll
    for (int k = 0; k < 8; ++k) { v[k] = cnt[tid * 8 + k]; s += v[k]; }
    int incl = s;
    #pragma unroll
    for (int off = 1; off < 64; off <<= 1) {
        int t = __shfl_up(incl, off);
        if (lane >= off) incl += t;
    }
    if (lane == 63) wsum[wv] = incl;
    __syncthreads();
    if (tid == 0) {
        int run = 0;
        #pragma unroll
        for (int w = 0; w < 4; ++w) { wpre[w] = run; run += wsum[w]; }
    }
    __syncthreads();
    int ex = wpre[wv] + incl - s;
    #pragma unroll
    for (int k = 0; k < 8; ++k) {
        int j = tid * 8 + k;
        bstart[j] = ex;
        bcur[j] = ex;
        ex += v[k];
    }
}

// ---------------- C: bin entries bucket-contiguous (tile counting-sort) ----------------
// e64: bits[0:32)=(col<<15)|bf16val15, bits[32:38)=row&63, bits[48:)=bucket
__global__ __launch_bounds__(BINBLK) void k_bin(const int* __restrict__ rows,
                                                const int* __restrict__ cols,
                                                const float* __restrict__ vals, int n,
                                                int* __restrict__ bcur,
                                                unsigned long long* __restrict__ e64) {
    __shared__ unsigned long long stage[TILE];   // 64 KB
    __shared__ int lh[NBMAX];
    __shared__ int lpos[NBMAX];
    __shared__ int gbase[NBMAX];
    __shared__ int csum[NBMAX / 64];
    int tid = threadIdx.x, lane = tid & 63, wv = tid >> 6;   // wv 0..15
    int ntiles = (n + TILE - 1) / TILE;
    for (int tile = blockIdx.x; tile < ntiles; tile += gridDim.x) {
        int base = tile * TILE;
        int cnt_t = min(TILE, n - base);
        for (int j = tid; j < NBMAX; j += BINBLK) lh[j] = 0;
        __syncthreads();
        unsigned long long e[TILE / BINBLK];
        #pragma unroll 4
        for (int k = 0; k < TILE / BINBLK; ++k) {
            int i = base + k * BINBLK + tid;
            e[k] = 0ull;
            if (i < n) {
                int r = rows[i];
                int b = r >> BSHIFT;
                u32 lo = ((u32)cols[i] << 15) | (u32)f2bf(vals[i]);
                e[k] = ((unsigned long long)(r & 63) << 32) | (unsigned long long)lo
                     | ((unsigned long long)b << 48);
                atomicAdd(&lh[b], 1);
            }
        }
        __syncthreads();
        for (int c = wv; c < NBMAX / 64; c += BINBLK / 64) {
            int v = lh[c * 64 + lane];
            int incl = v;
            #pragma unroll
            for (int off = 1; off < 64; off <<= 1) {
                int t = __shfl_up(incl, off);
                if (lane >= off) incl += t;
            }
            lpos[c * 64 + lane] = incl - v;
            if (lane == 63) csum[c] = incl;
        }
        __syncthreads();
        if (tid < 64) {
            int v = (lane < NBMAX / 64) ? csum[lane] : 0;
            int incl = v;
            #pragma unroll
            for (int off = 1; off < 32; off <<= 1) {
                int t = __shfl_up(incl, off);
                if (lane >= off) incl += t;
            }
            if (lane < NBMAX / 64) csum[lane] = incl - v;
        }
        __syncthreads();
        for (int j = tid; j < NBMAX; j += BINBLK) {
            int c0 = lh[j];
            int ex = lpos[j] + csum[j >> 6];
            lpos[j] = ex;
            lh[j] = ex;
            if (c0 > 0) gbase[j] = atomicAdd(&bcur[j], c0);
        }
        __syncthreads();
        #pragma unroll 4
        for (int k = 0; k < TILE / BINBLK; ++k) {
            int i = base + k * BINBLK + tid;
            if (i < n) {
                int b = (int)(e[k] >> 48);
                int s = atomicAdd(&lh[b], 1);
                stage[s] = e[k];
            }
        }
        __syncthreads();
        for (int s = tid; s < cnt_t; s += BINBLK) {
            unsigned long long ev = stage[s];
            int b = (int)(ev >> 48);
            e64[(size_t)gbase[b] + (s - lpos[b])] = ev;
        }
        __syncthreads();
    }
}

// ---------------- fp32 -> bf16 table conversion ----------------
__global__ __launch_bounds__(256) void k_cvt(const float* __restrict__ src,
                                             unsigned short* __restrict__ dst, int n4) {
    int i = blockIdx.x * blockDim.x + threadIdx.x;
    if (i >= n4) return;
    v4f f = *(const v4f*)(src + (size_t)i * 4);
    ushort4 o;
    o.x = f2bf(f.x); o.y = f2bf(f.y); o.z = f2bf(f.z); o.w = f2bf(f.w);
    *(ushort4*)(dst + (size_t)i * 4) = o;
}

// ---------------- D: bucket-SpMM, LDS row-sort + async gather pipeline ----------------
// One block per bucket. Chunk -> LDS row-sort (64 bins). Compute: each wave owns 8 rows,
// walks its sorted entry range one entry/iter: consume entry j's 256B row from a private
// 16-slot LDS ring (ds_read_b32, lane = cols 2l,2l+1) and issue global_load_lds for j+D.
// Zero VGPRs per outstanding load -> depth D=8/wave, 24 waves/CU => ~49KB in flight/CU.
// Clamped re-issue of the last entry keeps vmcnt invariant exactly D (same-address
// rewrites are benign). All control flow is wave-uniform.
template<int TBL32>
__global__ __launch_bounds__(512) void k_bspmm(const unsigned long long* __restrict__ e64,
                                               const int* __restrict__ bstart,
                                               const int* __restrict__ bcnt,
                                               const void* __restrict__ table,
                                               void* __restrict__ out,
                                               int nrows, int out_fp32) {
    constexpr int D  = 8;                 // outstanding gathers per wave
    constexpr int RS = 2 * D;             // ring slots
    constexpr int RW = TBL32 ? 128 : 64;  // u32 per slot (256B bf16 row / 512B fp32 row)
    __shared__ u32 ent[CHUNK];            // 16 KB
    __shared__ int rh[64];
    __shared__ int rptr[65];
    __shared__ u32 ring[8][RS][RW];       // 32 KB (bf16) / 64 KB (fp32)
    int b = blockIdx.x;
    int r0 = b << BSHIFT;
    int tid = threadIdx.x, lane = tid & 63, wv = tid >> 6;
    int beg = bstart[b], cnt = bcnt[b];
    const unsigned short* t16 = (const unsigned short*)table;
    const float* t32 = (const float*)table;
    float a0[8], a1[8];
    #pragma unroll
    for (int t = 0; t < 8; ++t) { a0[t] = 0.f; a1[t] = 0.f; }
    for (int cb = 0; cb < cnt; cb += CHUNK) {
        int cn = min(CHUNK, cnt - cb);
        if (tid < 64) rh[tid] = 0;
        __syncthreads();
        unsigned long long e[8];
        #pragma unroll
        for (int k = 0; k < 8; ++k) {
            int idx = k * 512 + tid;
            e[k] = 0ull;
            if (idx < cn) {
                e[k] = e64[(size_t)beg + cb + idx];
                atomicAdd(&rh[(int)(e[k] >> 32) & 63], 1);
            }
        }
        __syncthreads();
        if (tid < 64) {             // wave-0 scan of 64 row counts
            int v = rh[tid];
            int incl = v;
            #pragma unroll
            for (int off = 1; off < 64; off <<= 1) {
                int t = __shfl_up(incl, off);
                if (lane >= off) incl += t;
            }
            rptr[tid] = incl - v;
            if (tid == 63) rptr[64] = incl;
            rh[tid] = incl - v;     // becomes cursor
        }
        __syncthreads();
        #pragma unroll
        for (int k = 0; k < 8; ++k) {
            int idx = k * 512 + tid;
            if (idx < cn) {
                int row = (int)(e[k] >> 32) & 63;
                int p = atomicAdd(&rh[row], 1);
                ent[p] = (u32)e[k];
            }
        }
        __syncthreads();
        // compute: wave wv owns local rows [wv*8, wv*8+8) -> entry range [j0, j1)
        int j0 = rptr[wv * 8], j1 = rptr[wv * 8 + 8];
        if (j0 < j1) {
            int jl = j1 - 1;
            // prologue: issue D loads (clamped)
            #pragma unroll
            for (int p = 0; p < D; ++p) {
                int jn = j0 + p; if (jn > jl) jn = jl;
                u32 en = ent[jn];
                int sn = jn & (RS - 1);
                if (!TBL32) {
                    gl_lds(t16 + (((size_t)(en >> 15)) << 7) + (lane << 1), &ring[wv][sn][0]);
                } else {
                    gl_lds(t32 + (((size_t)(en >> 15)) << 7) + (lane << 1), &ring[wv][sn][0]);
                    gl_lds(t32 + (((size_t)(en >> 15)) << 7) + (lane << 1) + 1, &ring[wv][sn][64]);
                }
            }
            #pragma unroll
            for (int t = 0; t < 8; ++t) {
                int l = wv * 8 + t;
                int je = rptr[l + 1];
                for (int j = rptr[l]; j < je; ++j) {
                    if (!TBL32) asm volatile("s_waitcnt vmcnt(7)" ::: "memory");
                    else        asm volatile("s_waitcnt vmcnt(14)" ::: "memory");
                    int sl = j & (RS - 1);
                    u32 ev = ent[j];
                    float v = bfv(ev);
                    if (!TBL32) {
                        u32 w = ring[wv][sl][lane];
                        a0[t] = fmaf(v, bf_lo(w), a0[t]);
                        a1[t] = fmaf(v, bf_hi(w), a1[t]);
                    } else {
                        float w0 = __builtin_bit_cast(float, ring[wv][sl][lane]);
                        float w1 = __builtin_bit_cast(float, ring[wv][sl][64 + lane]);
                        a0[t] = fmaf(v, w0, a0[t]);
                        a1[t] = fmaf(v, w1, a1[t]);
                    }
                    int jn = j + D; if (jn > jl) jn = jl;
                    u32 en = ent[jn];
                    int sn = jn & (RS - 1);
                    if (!TBL32) {
                        gl_lds(t16 + (((size_t)(en >> 15)) << 7) + (lane << 1), &ring[wv][sn][0]);
                    } else {
                        gl_lds(t32 + (((size_t)(en >> 15)) << 7) + (lane << 1), &ring[wv][sn][0]);
                        gl_lds(t32 + (((size_t)(en >> 15)) << 7) + (lane << 1) + 1, &ring[wv][sn][64]);
                    }
                }
            }
        }
        __syncthreads();
    }
    int nr = min(64, nrows - r0);
    #pragma unroll
    for (int t = 0; t < 8; ++t) {
        int l = wv * 8 + t;
        if (l < nr) {
            if (out_fp32) {
                float2 o; o.x = a0[t]; o.y = a1[t];
                *(float2*)((float*)out + (((size_t)(r0 + l)) << 7) + (lane << 1)) = o;
            } else {
                u32 ov = (u32)f2bf(a0[t]) | ((u32)f2bf(a1[t]) << 16);
                *(u32*)((unsigned short*)out + (((size_t)(r0 + l)) << 7) + (lane << 1)) = ov;
            }
        }
    }
}

// ---------------- weight prep: Wc = [Wp@Wf_top ; We@Wf_bot], B-fragment packed ----------------
__global__ __launch_bounds__(128) void k_wprep(const float* __restrict__ Wp,
                                               const float* __restrict__ We,
                                               const float* __restrict__ Wf,
                                               unsigned short* __restrict__ wc) {
    int k = blockIdx.x;    // 0..255
    int n = threadIdx.x;   // 0..127
    const float* wrow = (k < 128) ? (Wp + (size_t)k * EMB) : (We + (size_t)(k - 128) * EMB);
    float acc = 0.f;
    #pragma unroll 4
    for (int j = 0; j < EMB; ++j)
        acc = fmaf(wrow[j], Wf[(size_t)((k < 128) ? j : (128 + j)) * EMB + n], acc);
    wc[(((k >> 3) * EMB) + n) * 8 + (k & 7)] = f2bf(acc);
}

// ---------------- fused GEMM (MFMA 16x16x32 bf16): M=nrows, K=256, N=128 ----------------
__global__ __launch_bounds__(256) void k_fused(const unsigned short* __restrict__ poi_agg,
                                               const float* __restrict__ edge,
                                               const unsigned short* __restrict__ wc,
                                               float* __restrict__ fused32,
                                               unsigned short* __restrict__ fused16, int nrows) {
    __shared__ __align__(16) unsigned short lds_w[32768];   // 64 KB packed B
    {
        const uint4* s = (const uint4*)wc;
        uint4* d = (uint4*)lds_w;
        #pragma unroll
        for (int i = 0; i < 16; ++i) d[threadIdx.x + i * 256] = s[threadIdx.x + i * 256];
    }
    __syncthreads();
    int lane = threadIdx.x & 63;
    int row_base = blockIdx.x * 64 + (threadIdx.x >> 6) * 16;
    int m = lane & 15, kq = lane >> 4;
    int arow = row_base + m;
    if (arow >= nrows) arow = nrows - 1;
    const unsigned short* ap_p = poi_agg + (size_t)arow * EMB;
    const float* ap_e = edge + (size_t)arow * EMB;
    v4f zero = {0.f, 0.f, 0.f, 0.f};
    v4f acc[8];
    #pragma unroll
    for (int t = 0; t < 8; ++t) acc[t] = zero;
    #pragma unroll
    for (int kt = 0; kt < 8; ++kt) {
        v8s a;
        if (kt < 4) {
            a = *(const v8s*)(ap_p + kt * 32 + kq * 8);
        } else {
            int k0 = (kt - 4) * 32 + kq * 8;
            v4f f0 = *(const v4f*)(ap_e + k0);
            v4f f1 = *(const v4f*)(ap_e + k0 + 4);
            a[0] = (short)f2bf(f0.x); a[1] = (short)f2bf(f0.y);
            a[2] = (short)f2bf(f0.z); a[3] = (short)f2bf(f0.w);
            a[4] = (short)f2bf(f1.x); a[5] = (short)f2bf(f1.y);
            a[6] = (short)f2bf(f1.z); a[7] = (short)f2bf(f1.w);
        }
        int kk = kt * 4 + kq;
        #pragma unroll
        for (int nt = 0; nt < 8; ++nt) {
            v8s bfr = *(const v8s*)(lds_w + ((kk * EMB + nt * 16 + m) << 3));
            acc[nt] = __builtin_amdgcn_mfma_f32_16x16x32_bf16(a, bfr, acc[nt], 0, 0, 0);
        }
    }
    #pragma unroll
    for (int r = 0; r < 4; ++r) {
        int ro = row_base + kq * 4 + r;
        if (ro >= nrows) continue;
        #pragma unroll
        for (int nt = 0; nt < 8; ++nt) {
            float x = acc[nt][r];
            size_t o = (size_t)ro * EMB + nt * 16 + m;
            fused32[o] = x;
            if (fused16) fused16[o] = f2bf(x);
        }
    }
}

extern "C" void kernel_launch(void* const* d_in, const int* in_sizes, int n_in,
                              void* d_out, int out_size, void* d_ws, size_t ws_size,
                              hipStream_t stream) {
    const float* poi  = (const float*)d_in[0];
    const float* edge = (const float*)d_in[1];
    const int* pte_rows = (const int*)d_in[2];
    const int* pte_cols = (const int*)d_in[3];
    const float* pte_vals = (const float*)d_in[4];
    const int* etp_rows = (const int*)d_in[5];
    const int* etp_cols = (const int*)d_in[6];
    const float* etp_vals = (const float*)d_in[7];
    const float* Wp = (const float*)d_in[8];
    const float* We = (const float*)d_in[9];
    const float* Wf = (const float*)d_in[10];

    int n_poi  = in_sizes[0] / EMB;   // 100000
    int n_edge = in_sizes[1] / EMB;   // 50000
    int nnz1 = in_sizes[2];           // 3.2M
    int nnz2 = in_sizes[5];           // 3.2M

    char* ws = (char*)d_ws;
    size_t off = 0;
    auto alloc = [&](size_t bytes) -> char* {
        char* p = ws + off;
        off = (off + bytes + 255) & ~(size_t)255;
        return p;
    };
    int* bcnt   = (int*)alloc(NBMAX * 4);
    int* bstart = (int*)alloc(NBMAX * 4);
    int* bcur   = (int*)alloc(NBMAX * 4);
    unsigned short* wc = (unsigned short*)alloc((size_t)2 * EMB * EMB * 2);
    int nnz_max = (nnz1 > nnz2) ? nnz1 : nnz2;
    unsigned long long* e64 = (unsigned long long*)alloc((size_t)nnz_max * 8);  // reused pte -> etp
    // optional bf16 copy of fused (halves spmm#2 gather bytes) — only if ws allows
    size_t f16_bytes = (size_t)n_edge * EMB * 2;
    unsigned short* fused16 = nullptr;
    if (off + f16_bytes <= ws_size) fused16 = (unsigned short*)alloc(f16_bytes);

    // d_out parking: output-0 region (51.2 MB) holds poi_bf + poi_agg until spmm#2
    float* out_prop  = (float*)d_out;                                   // [n_poi][128] fp32
    float* out_fused = out_prop + (size_t)n_poi * EMB;                  // [n_edge][128] fp32
    unsigned short* poi_bf  = (unsigned short*)d_out;                   // 25.6 MB bf16
    unsigned short* poi_agg = poi_bf + (size_t)n_poi * EMB;             // 12.8 MB bf16

    int nb1 = (n_edge + 63) >> BSHIFT;   // 782
    int nb2 = (n_poi + 63) >> BSHIFT;    // 1563

    // ---- pte binning ----
    hipMemsetAsync(bcnt, 0, NBMAX * 4, stream);
    k_bcount<<<256, 256, 0, stream>>>(pte_rows, nnz1, bcnt);
    k_bscan<<<1, 256, 0, stream>>>(bcnt, bstart, bcur);
    k_bin<<<256, BINBLK, 0, stream>>>(pte_rows, pte_cols, pte_vals, nnz1, bcur, e64);

    k_cvt<<<(n_poi * EMB / 4 + 255) / 256, 256, 0, stream>>>(poi, poi_bf, n_poi * EMB / 4);
    k_wprep<<<256, 128, 0, stream>>>(Wp, We, Wf, wc);

    // spmm#1: poi_agg[e] = sum vals * poi[col]  (bf16 table -> bf16 out)
    k_bspmm<0><<<nb1, 512, 0, stream>>>(e64, bstart, bcnt, poi_bf, poi_agg, n_edge, 0);
    // fused = poi_agg @ (Wp@Wf_top) + edge @ (We@Wf_bot) -> output 1 (fp32) [+ bf16 copy]
    k_fused<<<(n_edge + 63) / 64, 256, 0, stream>>>(poi_agg, edge, wc, out_fused, fused16, n_edge);

    // ---- etp binning (e64 reused after spmm#1 consumed it) ----
    hipMemsetAsync(bcnt, 0, NBMAX * 4, stream);
    k_bcount<<<256, 256, 0, stream>>>(etp_rows, nnz2, bcnt);
    k_bscan<<<1, 256, 0, stream>>>(bcnt, bstart, bcur);
    k_bin<<<256, BINBLK, 0, stream>>>(etp_rows, etp_cols, etp_vals, nnz2, bcur, e64);

    // spmm#2: propagated_poi = spmm(etp, fused) -> output 0 (fp32)
    if (fused16)
        k_bspmm<0><<<nb2, 512, 0, stream>>>(e64, bstart, bcnt, fused16, out_prop, n_poi, 1);
    else
        k_bspmm<1><<<nb2, 512, 0, stream>>>(e64, bstart, bcnt, out_fused, out_prop, n_poi, 1);
}

// Round 4
// 592.210 us; speedup vs baseline: 1.5654x; 1.5654x over previous
//
#include <hip/hip_runtime.h>

#define EMB 128
#define NBMAX 2048     // max buckets (etp: 1563)
#define BSHIFT 6       // 64 rows per bucket
#define TILE 4096      // entries per k_bin tile
#define BINBLK 512     // k_bin threads; ~52KB LDS -> 3 blocks/CU, 24 waves/CU
#define CHUNK 4096     // entries per k_bspmm LDS chunk

typedef float v4f __attribute__((ext_vector_type(4)));
typedef short v8s __attribute__((ext_vector_type(8)));
typedef unsigned int u32;
typedef unsigned long long u64;

__device__ inline float bf_lo(u32 u) { return __builtin_bit_cast(float, u << 16); }
__device__ inline float bf_hi(u32 u) { return __builtin_bit_cast(float, u & 0xffff0000u); }
__device__ inline float bfv(u32 e) { return __builtin_bit_cast(float, (e & 0x7FFFu) << 16); }
__device__ inline unsigned short f2bf(float x) {
    u32 u = __builtin_bit_cast(u32, x);
    return (unsigned short)((u + 0x7fffu + ((u >> 16) & 1u)) >> 16);   // RNE
}

// ---------------- A: bucket counts (LDS-privatized) ----------------
__global__ __launch_bounds__(256) void k_bcount(const int* __restrict__ rows, int n,
                                                int* __restrict__ cnt) {
    __shared__ int lh[NBMAX];
    for (int j = threadIdx.x; j < NBMAX; j += 256) lh[j] = 0;
    __syncthreads();
    for (int i = blockIdx.x * 256 + threadIdx.x; i < n; i += gridDim.x * 256)
        atomicAdd(&lh[rows[i] >> BSHIFT], 1);
    __syncthreads();
    for (int j = threadIdx.x; j < NBMAX; j += 256)
        if (lh[j]) atomicAdd(&cnt[j], lh[j]);
}

// ---------------- B: exclusive scan of NBMAX bucket counts -> bstart, bcur ----------------
__global__ __launch_bounds__(256) void k_bscan(const int* __restrict__ cnt,
                                               int* __restrict__ bstart, int* __restrict__ bcur) {
    __shared__ int wsum[4];
    __shared__ int wpre[4];
    int tid = threadIdx.x, lane = tid & 63, wv = tid >> 6;
    int v[8];
    int s = 0;
    #pragma unroll
    for (int k = 0; k < 8; ++k) { v[k] = cnt[tid * 8 + k]; s += v[k]; }
    int incl = s;
    #pragma unroll
    for (int off = 1; off < 64; off <<= 1) {
        int t = __shfl_up(incl, off);
        if (lane >= off) incl += t;
    }
    if (lane == 63) wsum[wv] = incl;
    __syncthreads();
    if (tid == 0) {
        int run = 0;
        #pragma unroll
        for (int w = 0; w < 4; ++w) { wpre[w] = run; run += wsum[w]; }
    }
    __syncthreads();
    int ex = wpre[wv] + incl - s;
    #pragma unroll
    for (int k = 0; k < 8; ++k) {
        int j = tid * 8 + k;
        bstart[j] = ex;
        bcur[j] = ex;
        ex += v[k];
    }
}

// ---------------- C: bin entries bucket-contiguous (tile counting-sort) ----------------
// e64: bits[0:32)=(col<<15)|bf16val15, bits[32:38)=row&63  (bucket NOT stored; bspmm
// doesn't need it). Stage split into 32/16/8-bit arrays: 7B/entry; TILE=4096, 512 thr
// -> ~52KB LDS -> 3 blocks/CU (phase latency of one block hidden by the other two).
__global__ __launch_bounds__(BINBLK) void k_bin(const int* __restrict__ rows,
                                                const int* __restrict__ cols,
                                                const float* __restrict__ vals, int n,
                                                int* __restrict__ bcur,
                                                u64* __restrict__ e64) {
    __shared__ u32 stage32[TILE];              // 16 KB: (col<<15)|val15
    __shared__ unsigned short stage16[TILE];   // 8 KB: bucket
    __shared__ unsigned char stage8[TILE];     // 4 KB: row&63
    __shared__ int lh[NBMAX];                  // 8 KB
    __shared__ int lpos[NBMAX];                // 8 KB
    __shared__ int gbase[NBMAX];               // 8 KB
    __shared__ int csum[NBMAX / 64];           // 128 B
    int tid = threadIdx.x, lane = tid & 63, wv = tid >> 6;   // wv 0..7
    int ntiles = (n + TILE - 1) / TILE;
    for (int tile = blockIdx.x; tile < ntiles; tile += gridDim.x) {
        int base = tile * TILE;
        int cnt_t = min(TILE, n - base);
        for (int j = tid; j < NBMAX; j += BINBLK) lh[j] = 0;
        __syncthreads();
        u64 e[TILE / BINBLK];                  // 8 entries/thread
        #pragma unroll
        for (int k = 0; k < TILE / BINBLK; ++k) {
            int i = base + k * BINBLK + tid;
            e[k] = 0ull;
            if (i < n) {
                int r = rows[i];
                int b = r >> BSHIFT;
                u32 lo = ((u32)cols[i] << 15) | (u32)f2bf(vals[i]);
                e[k] = ((u64)(r & 63) << 32) | (u64)lo | ((u64)b << 48);
                atomicAdd(&lh[b], 1);
            }
        }
        __syncthreads();
        // per-bucket exclusive scan within tile (2048 buckets, 64-wide groups)
        for (int c = wv; c < NBMAX / 64; c += BINBLK / 64) {
            int v = lh[c * 64 + lane];
            int incl = v;
            #pragma unroll
            for (int off = 1; off < 64; off <<= 1) {
                int t = __shfl_up(incl, off);
                if (lane >= off) incl += t;
            }
            lpos[c * 64 + lane] = incl - v;
            if (lane == 63) csum[c] = incl;
        }
        __syncthreads();
        if (tid < 64) {
            int v = (lane < NBMAX / 64) ? csum[lane] : 0;
            int incl = v;
            #pragma unroll
            for (int off = 1; off < 32; off <<= 1) {
                int t = __shfl_up(incl, off);
                if (lane >= off) incl += t;
            }
            if (lane < NBMAX / 64) csum[lane] = incl - v;
        }
        __syncthreads();
        for (int j = tid; j < NBMAX; j += BINBLK) {
            int c0 = lh[j];
            int ex = lpos[j] + csum[j >> 6];
            lpos[j] = ex;
            lh[j] = ex;
            if (c0 > 0) gbase[j] = atomicAdd(&bcur[j], c0);
        }
        __syncthreads();
        #pragma unroll
        for (int k = 0; k < TILE / BINBLK; ++k) {
            int i = base + k * BINBLK + tid;
            if (i < n) {
                int b = (int)(e[k] >> 48);
                int s = atomicAdd(&lh[b], 1);
                stage32[s] = (u32)e[k];
                stage16[s] = (unsigned short)b;
                stage8[s]  = (unsigned char)((e[k] >> 32) & 63);
            }
        }
        __syncthreads();
        for (int s = tid; s < cnt_t; s += BINBLK) {
            int b = stage16[s];
            e64[(size_t)gbase[b] + (s - lpos[b])] =
                ((u64)stage8[s] << 32) | (u64)stage32[s];
        }
        __syncthreads();
    }
}

// ---------------- fp32 -> bf16 table conversion ----------------
__global__ __launch_bounds__(256) void k_cvt(const float* __restrict__ src,
                                             unsigned short* __restrict__ dst, int n4) {
    int i = blockIdx.x * blockDim.x + threadIdx.x;
    if (i >= n4) return;
    v4f f = *(const v4f*)(src + (size_t)i * 4);
    ushort4 o;
    o.x = f2bf(f.x); o.y = f2bf(f.y); o.z = f2bf(f.z); o.w = f2bf(f.w);
    *(ushort4*)(dst + (size_t)i * 4) = o;
}

// ---------------- D: bucket-SpMM, LDS row-sort + register accumulation ----------------
// (Round-2 engine, best measured: ~121us.) One block per bucket. Chunk -> LDS row-sort
// (64 bins) -> each wave owns 8 rows; halves h=0/1 take even/odd entries, 8B loads/lane,
// unroll-16 -> 8 gather loads in flight per wave.
__global__ __launch_bounds__(512) void k_bspmm(const u64* __restrict__ e64,
                                               const int* __restrict__ bstart,
                                               const int* __restrict__ bcnt,
                                               const void* __restrict__ table,
                                               void* __restrict__ out,
                                               int nrows, int tbl_fp32, int out_fp32) {
    __shared__ u32 ent[CHUNK];   // 16 KB
    __shared__ int rh[64];
    __shared__ int rptr[65];
    int b = blockIdx.x;
    int r0 = b << BSHIFT;
    int tid = threadIdx.x, lane = tid & 63, wv = tid >> 6;
    int h = lane >> 5;       // half: entry selector
    int m = lane & 31;       // col group: cols m*4 .. m*4+3
    int beg = bstart[b], cnt = bcnt[b];
    const unsigned short* t16 = (const unsigned short*)table;
    const float* t32 = (const float*)table;
    float a[8][4];
    #pragma unroll
    for (int t = 0; t < 8; ++t) {
        #pragma unroll
        for (int c = 0; c < 4; ++c) a[t][c] = 0.f;
    }
    for (int cb = 0; cb < cnt; cb += CHUNK) {
        int cn = min(CHUNK, cnt - cb);
        if (tid < 64) rh[tid] = 0;
        __syncthreads();
        u64 e[8];
        #pragma unroll
        for (int k = 0; k < 8; ++k) {
            int idx = k * 512 + tid;
            e[k] = 0ull;
            if (idx < cn) {
                e[k] = e64[(size_t)beg + cb + idx];
                atomicAdd(&rh[(int)(e[k] >> 32) & 63], 1);
            }
        }
        __syncthreads();
        if (tid < 64) {             // wave-0 scan of 64 row counts
            int v = rh[tid];
            int incl = v;
            #pragma unroll
            for (int off = 1; off < 64; off <<= 1) {
                int t = __shfl_up(incl, off);
                if (lane >= off) incl += t;
            }
            rptr[tid] = incl - v;
            if (tid == 63) rptr[64] = incl;
            rh[tid] = incl - v;     // becomes cursor
        }
        __syncthreads();
        #pragma unroll
        for (int k = 0; k < 8; ++k) {
            int idx = k * 512 + tid;
            if (idx < cn) {
                int row = (int)(e[k] >> 32) & 63;
                int p = atomicAdd(&rh[row], 1);
                ent[p] = (u32)e[k];
            }
        }
        __syncthreads();
        // compute: wave wv owns local rows [wv*8, wv*8+8)
        #pragma unroll
        for (int t = 0; t < 8; ++t) {
            int l = wv * 8 + t;
            int j = rptr[l], je = rptr[l + 1];
            if (tbl_fp32) {
                for (; j + 16 <= je; j += 16) {
                    u32 ee[8];
                    #pragma unroll
                    for (int p = 0; p < 8; ++p) ee[p] = ent[j + 2 * p + h];
                    v4f uu[8];
                    #pragma unroll
                    for (int p = 0; p < 8; ++p)
                        uu[p] = *(const v4f*)(t32 + (((size_t)(ee[p] >> 15)) << 7) + (m << 2));
                    #pragma unroll
                    for (int p = 0; p < 8; ++p) {
                        float v0 = bfv(ee[p]);
                        #pragma unroll
                        for (int c = 0; c < 4; ++c) a[t][c] = fmaf(v0, uu[p][c], a[t][c]);
                    }
                }
                for (; j + 8 <= je; j += 8) {
                    u32 e0 = ent[j + h], e1 = ent[j + 2 + h];
                    u32 e2 = ent[j + 4 + h], e3 = ent[j + 6 + h];
                    v4f u0 = *(const v4f*)(t32 + (((size_t)(e0 >> 15)) << 7) + (m << 2));
                    v4f u1 = *(const v4f*)(t32 + (((size_t)(e1 >> 15)) << 7) + (m << 2));
                    v4f u2 = *(const v4f*)(t32 + (((size_t)(e2 >> 15)) << 7) + (m << 2));
                    v4f u3 = *(const v4f*)(t32 + (((size_t)(e3 >> 15)) << 7) + (m << 2));
                    float v0 = bfv(e0), v1 = bfv(e1), v2 = bfv(e2), v3 = bfv(e3);
                    #pragma unroll
                    for (int c = 0; c < 4; ++c) a[t][c] = fmaf(v0, u0[c], a[t][c]);
                    #pragma unroll
                    for (int c = 0; c < 4; ++c) a[t][c] = fmaf(v1, u1[c], a[t][c]);
                    #pragma unroll
                    for (int c = 0; c < 4; ++c) a[t][c] = fmaf(v2, u2[c], a[t][c]);
                    #pragma unroll
                    for (int c = 0; c < 4; ++c) a[t][c] = fmaf(v3, u3[c], a[t][c]);
                }
                for (; j < je; j += 2) {
                    u32 e0 = (j + h < je) ? ent[j + h] : 0u;
                    v4f u0 = *(const v4f*)(t32 + (((size_t)(e0 >> 15)) << 7) + (m << 2));
                    float v0 = bfv(e0);
                    #pragma unroll
                    for (int c = 0; c < 4; ++c) a[t][c] = fmaf(v0, u0[c], a[t][c]);
                }
            } else {
                for (; j + 16 <= je; j += 16) {
                    u32 ee[8];
                    #pragma unroll
                    for (int p = 0; p < 8; ++p) ee[p] = ent[j + 2 * p + h];
                    uint2 uu[8];
                    #pragma unroll
                    for (int p = 0; p < 8; ++p)
                        uu[p] = *(const uint2*)(t16 + (((size_t)(ee[p] >> 15)) << 7) + (m << 2));
                    #pragma unroll
                    for (int p = 0; p < 8; ++p) {
                        float v0 = bfv(ee[p]);
                        a[t][0] = fmaf(v0, bf_lo(uu[p].x), a[t][0]);
                        a[t][1] = fmaf(v0, bf_hi(uu[p].x), a[t][1]);
                        a[t][2] = fmaf(v0, bf_lo(uu[p].y), a[t][2]);
                        a[t][3] = fmaf(v0, bf_hi(uu[p].y), a[t][3]);
                    }
                }
                for (; j + 8 <= je; j += 8) {
                    u32 e0 = ent[j + h], e1 = ent[j + 2 + h];
                    u32 e2 = ent[j + 4 + h], e3 = ent[j + 6 + h];
                    uint2 u0 = *(const uint2*)(t16 + (((size_t)(e0 >> 15)) << 7) + (m << 2));
                    uint2 u1 = *(const uint2*)(t16 + (((size_t)(e1 >> 15)) << 7) + (m << 2));
                    uint2 u2 = *(const uint2*)(t16 + (((size_t)(e2 >> 15)) << 7) + (m << 2));
                    uint2 u3 = *(const uint2*)(t16 + (((size_t)(e3 >> 15)) << 7) + (m << 2));
                    float v0 = bfv(e0), v1 = bfv(e1), v2 = bfv(e2), v3 = bfv(e3);
                    a[t][0] = fmaf(v0, bf_lo(u0.x), a[t][0]);
                    a[t][1] = fmaf(v0, bf_hi(u0.x), a[t][1]);
                    a[t][2] = fmaf(v0, bf_lo(u0.y), a[t][2]);
                    a[t][3] = fmaf(v0, bf_hi(u0.y), a[t][3]);
                    a[t][0] = fmaf(v1, bf_lo(u1.x), a[t][0]);
                    a[t][1] = fmaf(v1, bf_hi(u1.x), a[t][1]);
                    a[t][2] = fmaf(v1, bf_lo(u1.y), a[t][2]);
                    a[t][3] = fmaf(v1, bf_hi(u1.y), a[t][3]);
                    a[t][0] = fmaf(v2, bf_lo(u2.x), a[t][0]);
                    a[t][1] = fmaf(v2, bf_hi(u2.x), a[t][1]);
                    a[t][2] = fmaf(v2, bf_lo(u2.y), a[t][2]);
                    a[t][3] = fmaf(v2, bf_hi(u2.y), a[t][3]);
                    a[t][0] = fmaf(v3, bf_lo(u3.x), a[t][0]);
                    a[t][1] = fmaf(v3, bf_hi(u3.x), a[t][1]);
                    a[t][2] = fmaf(v3, bf_lo(u3.y), a[t][2]);
                    a[t][3] = fmaf(v3, bf_hi(u3.y), a[t][3]);
                }
                for (; j < je; j += 2) {
                    u32 e0 = (j + h < je) ? ent[j + h] : 0u;
                    uint2 u0 = *(const uint2*)(t16 + (((size_t)(e0 >> 15)) << 7) + (m << 2));
                    float v0 = bfv(e0);
                    a[t][0] = fmaf(v0, bf_lo(u0.x), a[t][0]);
                    a[t][1] = fmaf(v0, bf_hi(u0.x), a[t][1]);
                    a[t][2] = fmaf(v0, bf_lo(u0.y), a[t][2]);
                    a[t][3] = fmaf(v0, bf_hi(u0.y), a[t][3]);
                }
            }
        }
        __syncthreads();
    }
    int nr = min(64, nrows - r0);
    #pragma unroll
    for (int t = 0; t < 8; ++t) {
        // merge the two half-wave partial sums (entries were split even/odd across halves)
        #pragma unroll
        for (int c = 0; c < 4; ++c) a[t][c] += __shfl_xor(a[t][c], 32);
        int l = wv * 8 + t;
        if (l < nr && h == 0) {
            if (out_fp32) {
                v4f o = {a[t][0], a[t][1], a[t][2], a[t][3]};
                *(v4f*)((float*)out + (((size_t)(r0 + l)) << 7) + (m << 2)) = o;
            } else {
                uint2 ov;
                ov.x = (u32)f2bf(a[t][0]) | ((u32)f2bf(a[t][1]) << 16);
                ov.y = (u32)f2bf(a[t][2]) | ((u32)f2bf(a[t][3]) << 16);
                *(uint2*)((unsigned short*)out + (((size_t)(r0 + l)) << 7) + (m << 2)) = ov;
            }
        }
    }
}

// ---------------- weight prep: Wc = [Wp@Wf_top ; We@Wf_bot], B-fragment packed ----------------
__global__ __launch_bounds__(128) void k_wprep(const float* __restrict__ Wp,
                                               const float* __restrict__ We,
                                               const float* __restrict__ Wf,
                                               unsigned short* __restrict__ wc) {
    int k = blockIdx.x;    // 0..255
    int n = threadIdx.x;   // 0..127
    const float* wrow = (k < 128) ? (Wp + (size_t)k * EMB) : (We + (size_t)(k - 128) * EMB);
    float acc = 0.f;
    #pragma unroll 4
    for (int j = 0; j < EMB; ++j)
        acc = fmaf(wrow[j], Wf[(size_t)((k < 128) ? j : (128 + j)) * EMB + n], acc);
    wc[(((k >> 3) * EMB) + n) * 8 + (k & 7)] = f2bf(acc);
}

// ---------------- fused GEMM (MFMA 16x16x32 bf16): M=nrows, K=256, N=128 ----------------
__global__ __launch_bounds__(256) void k_fused(const unsigned short* __restrict__ poi_agg,
                                               const float* __restrict__ edge,
                                               const unsigned short* __restrict__ wc,
                                               float* __restrict__ fused32,
                                               unsigned short* __restrict__ fused16, int nrows) {
    __shared__ __align__(16) unsigned short lds_w[32768];   // 64 KB packed B
    {
        const uint4* s = (const uint4*)wc;
        uint4* d = (uint4*)lds_w;
        #pragma unroll
        for (int i = 0; i < 16; ++i) d[threadIdx.x + i * 256] = s[threadIdx.x + i * 256];
    }
    __syncthreads();
    int lane = threadIdx.x & 63;
    int row_base = blockIdx.x * 64 + (threadIdx.x >> 6) * 16;
    int m = lane & 15, kq = lane >> 4;
    int arow = row_base + m;
    if (arow >= nrows) arow = nrows - 1;
    const unsigned short* ap_p = poi_agg + (size_t)arow * EMB;
    const float* ap_e = edge + (size_t)arow * EMB;
    v4f zero = {0.f, 0.f, 0.f, 0.f};
    v4f acc[8];
    #pragma unroll
    for (int t = 0; t < 8; ++t) acc[t] = zero;
    #pragma unroll
    for (int kt = 0; kt < 8; ++kt) {
        v8s a;
        if (kt < 4) {
            a = *(const v8s*)(ap_p + kt * 32 + kq * 8);
        } else {
            int k0 = (kt - 4) * 32 + kq * 8;
            v4f f0 = *(const v4f*)(ap_e + k0);
            v4f f1 = *(const v4f*)(ap_e + k0 + 4);
            a[0] = (short)f2bf(f0.x); a[1] = (short)f2bf(f0.y);
            a[2] = (short)f2bf(f0.z); a[3] = (short)f2bf(f0.w);
            a[4] = (short)f2bf(f1.x); a[5] = (short)f2bf(f1.y);
            a[6] = (short)f2bf(f1.z); a[7] = (short)f2bf(f1.w);
        }
        int kk = kt * 4 + kq;
        #pragma unroll
        for (int nt = 0; nt < 8; ++nt) {
            v8s bfr = *(const v8s*)(lds_w + ((kk * EMB + nt * 16 + m) << 3));
            acc[nt] = __builtin_amdgcn_mfma_f32_16x16x32_bf16(a, bfr, acc[nt], 0, 0, 0);
        }
    }
    #pragma unroll
    for (int r = 0; r < 4; ++r) {
        int ro = row_base + kq * 4 + r;
        if (ro >= nrows) continue;
        #pragma unroll
        for (int nt = 0; nt < 8; ++nt) {
            float x = acc[nt][r];
            size_t o = (size_t)ro * EMB + nt * 16 + m;
            fused32[o] = x;
            if (fused16) fused16[o] = f2bf(x);
        }
    }
}

extern "C" void kernel_launch(void* const* d_in, const int* in_sizes, int n_in,
                              void* d_out, int out_size, void* d_ws, size_t ws_size,
                              hipStream_t stream) {
    const float* poi  = (const float*)d_in[0];
    const float* edge = (const float*)d_in[1];
    const int* pte_rows = (const int*)d_in[2];
    const int* pte_cols = (const int*)d_in[3];
    const float* pte_vals = (const float*)d_in[4];
    const int* etp_rows = (const int*)d_in[5];
    const int* etp_cols = (const int*)d_in[6];
    const float* etp_vals = (const float*)d_in[7];
    const float* Wp = (const float*)d_in[8];
    const float* We = (const float*)d_in[9];
    const float* Wf = (const float*)d_in[10];

    int n_poi  = in_sizes[0] / EMB;   // 100000
    int n_edge = in_sizes[1] / EMB;   // 50000
    int nnz1 = in_sizes[2];           // 3.2M
    int nnz2 = in_sizes[5];           // 3.2M

    char* ws = (char*)d_ws;
    size_t off = 0;
    auto alloc = [&](size_t bytes) -> char* {
        char* p = ws + off;
        off = (off + bytes + 255) & ~(size_t)255;
        return p;
    };
    int* bcnt   = (int*)alloc(NBMAX * 4);
    int* bstart = (int*)alloc(NBMAX * 4);
    int* bcur   = (int*)alloc(NBMAX * 4);
    unsigned short* wc = (unsigned short*)alloc((size_t)2 * EMB * EMB * 2);
    int nnz_max = (nnz1 > nnz2) ? nnz1 : nnz2;
    u64* e64 = (u64*)alloc((size_t)nnz_max * 8);  // reused pte -> etp
    // optional bf16 copy of fused (halves spmm#2 gather bytes) — only if ws allows
    size_t f16_bytes = (size_t)n_edge * EMB * 2;
    unsigned short* fused16 = nullptr;
    if (off + f16_bytes <= ws_size) fused16 = (unsigned short*)alloc(f16_bytes);

    // d_out parking: output-0 region (51.2 MB) holds poi_bf + poi_agg until spmm#2
    float* out_prop  = (float*)d_out;                                   // [n_poi][128] fp32
    float* out_fused = out_prop + (size_t)n_poi * EMB;                  // [n_edge][128] fp32
    unsigned short* poi_bf  = (unsigned short*)d_out;                   // 25.6 MB bf16
    unsigned short* poi_agg = poi_bf + (size_t)n_poi * EMB;             // 12.8 MB bf16

    int nb1 = (n_edge + 63) >> BSHIFT;   // 782
    int nb2 = (n_poi + 63) >> BSHIFT;    // 1563

    // ---- pte binning ----
    hipMemsetAsync(bcnt, 0, NBMAX * 4, stream);
    k_bcount<<<256, 256, 0, stream>>>(pte_rows, nnz1, bcnt);
    k_bscan<<<1, 256, 0, stream>>>(bcnt, bstart, bcur);
    k_bin<<<768, BINBLK, 0, stream>>>(pte_rows, pte_cols, pte_vals, nnz1, bcur, e64);

    k_cvt<<<(n_poi * EMB / 4 + 255) / 256, 256, 0, stream>>>(poi, poi_bf, n_poi * EMB / 4);
    k_wprep<<<256, 128, 0, stream>>>(Wp, We, Wf, wc);

    // spmm#1: poi_agg[e] = sum vals * poi[col]  (bf16 table -> bf16 out)
    k_bspmm<<<nb1, 512, 0, stream>>>(e64, bstart, bcnt, poi_bf, poi_agg, n_edge, 0, 0);
    // fused = poi_agg @ (Wp@Wf_top) + edge @ (We@Wf_bot) -> output 1 (fp32) [+ bf16 copy]
    k_fused<<<(n_edge + 63) / 64, 256, 0, stream>>>(poi_agg, edge, wc, out_fused, fused16, n_edge);

    // ---- etp binning (e64 reused after spmm#1 consumed it) ----
    hipMemsetAsync(bcnt, 0, NBMAX * 4, stream);
    k_bcount<<<256, 256, 0, stream>>>(etp_rows, nnz2, bcnt);
    k_bscan<<<1, 256, 0, stream>>>(bcnt, bstart, bcur);
    k_bin<<<768, BINBLK, 0, stream>>>(etp_rows, etp_cols, etp_vals, nnz2, bcur, e64);

    // spmm#2: propagated_poi = spmm(etp, fused) -> output 0 (fp32)
    if (fused16)
        k_bspmm<<<nb2, 512, 0, stream>>>(e64, bstart, bcnt, fused16, out_prop, n_poi, 0, 1);
    else
        k_bspmm<<<nb2, 512, 0, stream>>>(e64, bstart, bcnt, out_fused, out_prop, n_poi, 1, 1);
}

// Round 5
// 547.273 us; speedup vs baseline: 1.6939x; 1.0821x over previous
//
#include <hip/hip_runtime.h>

#define EMB 128
#define NBMAX 2048     // max buckets (etp: 1563)
#define BSHIFT 6       // 64 rows per bucket
#define TILE 8192      // entries per k_bin tile
#define BINBLK 1024    // k_bin threads (16 waves; 2 blocks/CU at <80KB LDS)
#define CHUNK 4096     // entries per k_bspmm LDS chunk

typedef float v4f __attribute__((ext_vector_type(4)));
typedef short v8s __attribute__((ext_vector_type(8)));
typedef unsigned int u32;
typedef unsigned long long u64;

__device__ inline float bf_lo(u32 u) { return __builtin_bit_cast(float, u << 16); }
__device__ inline float bf_hi(u32 u) { return __builtin_bit_cast(float, u & 0xffff0000u); }
__device__ inline float bfv(u32 e) { return __builtin_bit_cast(float, (e & 0x7FFFu) << 16); }
__device__ inline unsigned short f2bf(float x) {
    u32 u = __builtin_bit_cast(u32, x);
    return (unsigned short)((u + 0x7fffu + ((u >> 16) & 1u)) >> 16);   // RNE
}

// ---------------- A: bucket counts (LDS-privatized) ----------------
__global__ __launch_bounds__(256) void k_bcount(const int* __restrict__ rows, int n,
                                                int* __restrict__ cnt) {
    __shared__ int lh[NBMAX];
    for (int j = threadIdx.x; j < NBMAX; j += 256) lh[j] = 0;
    __syncthreads();
    for (int i = blockIdx.x * 256 + threadIdx.x; i < n; i += gridDim.x * 256)
        atomicAdd(&lh[rows[i] >> BSHIFT], 1);
    __syncthreads();
    for (int j = threadIdx.x; j < NBMAX; j += 256)
        if (lh[j]) atomicAdd(&cnt[j], lh[j]);
}

// ---------------- B: exclusive scan of NBMAX bucket counts -> bstart, bcur ----------------
__global__ __launch_bounds__(256) void k_bscan(const int* __restrict__ cnt,
                                               int* __restrict__ bstart, int* __restrict__ bcur) {
    __shared__ int wsum[4];
    __shared__ int wpre[4];
    int tid = threadIdx.x, lane = tid & 63, wv = tid >> 6;
    int v[8];
    int s = 0;
    #pragma unroll
    for (int k = 0; k < 8; ++k) { v[k] = cnt[tid * 8 + k]; s += v[k]; }
    int incl = s;
    #pragma unroll
    for (int off = 1; off < 64; off <<= 1) {
        int t = __shfl_up(incl, off);
        if (lane >= off) incl += t;
    }
    if (lane == 63) wsum[wv] = incl;
    __syncthreads();
    if (tid == 0) {
        int run = 0;
        #pragma unroll
        for (int w = 0; w < 4; ++w) { wpre[w] = run; run += wsum[w]; }
    }
    __syncthreads();
    int ex = wpre[wv] + incl - s;
    #pragma unroll
    for (int k = 0; k < 8; ++k) {
        int j = tid * 8 + k;
        bstart[j] = ex;
        bcur[j] = ex;
        ex += v[k];
    }
}

// ---------------- C: bin entries bucket-contiguous (tile counting-sort) ----------------
// e64: bits[0:32)=(col<<15)|bf16val15, bits[32:38)=row&63 (bucket not stored).
// TILE=8192 @ 1024 thr (the R2-proven shape) with two occupancy fixes:
//  - stage split 32/16/8-bit: 7B/entry = 56KB (was 64KB u64)
//  - bucket tables templated to actual bucket count NBP (pte 832, etp 1600):
//    LDS 65.8/74.9KB -> 2 blocks/CU (32 waves/CU); table zero/scan passes shrink too.
template<int NBP>
__global__ __launch_bounds__(BINBLK, 8) void k_bin(const int* __restrict__ rows,
                                                   const int* __restrict__ cols,
                                                   const float* __restrict__ vals, int n,
                                                   int* __restrict__ bcur,
                                                   u64* __restrict__ e64) {
    constexpr int NGRP = NBP / 64;
    __shared__ u32 stage32[TILE];              // 32 KB: (col<<15)|val15
    __shared__ unsigned short stage16[TILE];   // 16 KB: bucket
    __shared__ unsigned char stage8[TILE];     // 8 KB: row&63
    __shared__ int lh[NBP];
    __shared__ int lpos[NBP];
    __shared__ int gbase[NBP];
    __shared__ int csum[NGRP];
    int tid = threadIdx.x, lane = tid & 63, wv = tid >> 6;   // wv 0..15
    int ntiles = (n + TILE - 1) / TILE;
    for (int tile = blockIdx.x; tile < ntiles; tile += gridDim.x) {
        int base = tile * TILE;
        int cnt_t = min(TILE, n - base);
        for (int j = tid; j < NBP; j += BINBLK) lh[j] = 0;
        __syncthreads();
        u64 e[TILE / BINBLK];                  // 8 entries/thread
        #pragma unroll
        for (int k = 0; k < TILE / BINBLK; ++k) {
            int i = base + k * BINBLK + tid;
            e[k] = 0ull;
            if (i < n) {
                int r = rows[i];
                int b = r >> BSHIFT;
                u32 lo = ((u32)cols[i] << 15) | (u32)f2bf(vals[i]);
                e[k] = ((u64)(r & 63) << 32) | (u64)lo | ((u64)b << 48);
                atomicAdd(&lh[b], 1);
            }
        }
        __syncthreads();
        // per-bucket exclusive scan within tile (NBP buckets, 64-wide groups)
        for (int c = wv; c < NGRP; c += BINBLK / 64) {
            int v = lh[c * 64 + lane];
            int incl = v;
            #pragma unroll
            for (int off = 1; off < 64; off <<= 1) {
                int t = __shfl_up(incl, off);
                if (lane >= off) incl += t;
            }
            lpos[c * 64 + lane] = incl - v;
            if (lane == 63) csum[c] = incl;
        }
        __syncthreads();
        if (tid < 64) {
            int v = (lane < NGRP) ? csum[lane] : 0;
            int incl = v;
            #pragma unroll
            for (int off = 1; off < 32; off <<= 1) {
                int t = __shfl_up(incl, off);
                if (lane >= off) incl += t;
            }
            if (lane < NGRP) csum[lane] = incl - v;
        }
        __syncthreads();
        for (int j = tid; j < NBP; j += BINBLK) {
            int c0 = lh[j];
            int ex = lpos[j] + csum[j >> 6];
            lpos[j] = ex;
            lh[j] = ex;
            if (c0 > 0) gbase[j] = atomicAdd(&bcur[j], c0);
        }
        __syncthreads();
        #pragma unroll
        for (int k = 0; k < TILE / BINBLK; ++k) {
            int i = base + k * BINBLK + tid;
            if (i < n) {
                int b = (int)(e[k] >> 48);
                int s = atomicAdd(&lh[b], 1);
                stage32[s] = (u32)e[k];
                stage16[s] = (unsigned short)b;
                stage8[s]  = (unsigned char)((e[k] >> 32) & 63);
            }
        }
        __syncthreads();
        for (int s = tid; s < cnt_t; s += BINBLK) {
            int b = stage16[s];
            e64[(size_t)gbase[b] + (s - lpos[b])] =
                ((u64)stage8[s] << 32) | (u64)stage32[s];
        }
        __syncthreads();
    }
}

// ---------------- fp32 -> bf16 table conversion ----------------
__global__ __launch_bounds__(256) void k_cvt(const float* __restrict__ src,
                                             unsigned short* __restrict__ dst, int n4) {
    int i = blockIdx.x * blockDim.x + threadIdx.x;
    if (i >= n4) return;
    v4f f = *(const v4f*)(src + (size_t)i * 4);
    ushort4 o;
    o.x = f2bf(f.x); o.y = f2bf(f.y); o.z = f2bf(f.z); o.w = f2bf(f.w);
    *(ushort4*)(dst + (size_t)i * 4) = o;
}

// ---------------- D: bucket-SpMM, LDS row-sort + register accumulation ----------------
// (Round-2 engine, best measured: ~121us.) One block per bucket. Chunk -> LDS row-sort
// (64 bins) -> each wave owns 8 rows; halves h=0/1 take even/odd entries, 8B loads/lane,
// unroll-16 -> 8 gather loads in flight per wave.
__global__ __launch_bounds__(512) void k_bspmm(const u64* __restrict__ e64,
                                               const int* __restrict__ bstart,
                                               const int* __restrict__ bcnt,
                                               const void* __restrict__ table,
                                               void* __restrict__ out,
                                               int nrows, int tbl_fp32, int out_fp32) {
    __shared__ u32 ent[CHUNK];   // 16 KB
    __shared__ int rh[64];
    __shared__ int rptr[65];
    int b = blockIdx.x;
    int r0 = b << BSHIFT;
    int tid = threadIdx.x, lane = tid & 63, wv = tid >> 6;
    int h = lane >> 5;       // half: entry selector
    int m = lane & 31;       // col group: cols m*4 .. m*4+3
    int beg = bstart[b], cnt = bcnt[b];
    const unsigned short* t16 = (const unsigned short*)table;
    const float* t32 = (const float*)table;
    float a[8][4];
    #pragma unroll
    for (int t = 0; t < 8; ++t) {
        #pragma unroll
        for (int c = 0; c < 4; ++c) a[t][c] = 0.f;
    }
    for (int cb = 0; cb < cnt; cb += CHUNK) {
        int cn = min(CHUNK, cnt - cb);
        if (tid < 64) rh[tid] = 0;
        __syncthreads();
        u64 e[8];
        #pragma unroll
        for (int k = 0; k < 8; ++k) {
            int idx = k * 512 + tid;
            e[k] = 0ull;
            if (idx < cn) {
                e[k] = e64[(size_t)beg + cb + idx];
                atomicAdd(&rh[(int)(e[k] >> 32) & 63], 1);
            }
        }
        __syncthreads();
        if (tid < 64) {             // wave-0 scan of 64 row counts
            int v = rh[tid];
            int incl = v;
            #pragma unroll
            for (int off = 1; off < 64; off <<= 1) {
                int t = __shfl_up(incl, off);
                if (lane >= off) incl += t;
            }
            rptr[tid] = incl - v;
            if (tid == 63) rptr[64] = incl;
            rh[tid] = incl - v;     // becomes cursor
        }
        __syncthreads();
        #pragma unroll
        for (int k = 0; k < 8; ++k) {
            int idx = k * 512 + tid;
            if (idx < cn) {
                int row = (int)(e[k] >> 32) & 63;
                int p = atomicAdd(&rh[row], 1);
                ent[p] = (u32)e[k];
            }
        }
        __syncthreads();
        // compute: wave wv owns local rows [wv*8, wv*8+8)
        #pragma unroll
        for (int t = 0; t < 8; ++t) {
            int l = wv * 8 + t;
            int j = rptr[l], je = rptr[l + 1];
            if (tbl_fp32) {
                for (; j + 16 <= je; j += 16) {
                    u32 ee[8];
                    #pragma unroll
                    for (int p = 0; p < 8; ++p) ee[p] = ent[j + 2 * p + h];
                    v4f uu[8];
                    #pragma unroll
                    for (int p = 0; p < 8; ++p)
                        uu[p] = *(const v4f*)(t32 + (((size_t)(ee[p] >> 15)) << 7) + (m << 2));
                    #pragma unroll
                    for (int p = 0; p < 8; ++p) {
                        float v0 = bfv(ee[p]);
                        #pragma unroll
                        for (int c = 0; c < 4; ++c) a[t][c] = fmaf(v0, uu[p][c], a[t][c]);
                    }
                }
                for (; j + 8 <= je; j += 8) {
                    u32 e0 = ent[j + h], e1 = ent[j + 2 + h];
                    u32 e2 = ent[j + 4 + h], e3 = ent[j + 6 + h];
                    v4f u0 = *(const v4f*)(t32 + (((size_t)(e0 >> 15)) << 7) + (m << 2));
                    v4f u1 = *(const v4f*)(t32 + (((size_t)(e1 >> 15)) << 7) + (m << 2));
                    v4f u2 = *(const v4f*)(t32 + (((size_t)(e2 >> 15)) << 7) + (m << 2));
                    v4f u3 = *(const v4f*)(t32 + (((size_t)(e3 >> 15)) << 7) + (m << 2));
                    float v0 = bfv(e0), v1 = bfv(e1), v2 = bfv(e2), v3 = bfv(e3);
                    #pragma unroll
                    for (int c = 0; c < 4; ++c) a[t][c] = fmaf(v0, u0[c], a[t][c]);
                    #pragma unroll
                    for (int c = 0; c < 4; ++c) a[t][c] = fmaf(v1, u1[c], a[t][c]);
                    #pragma unroll
                    for (int c = 0; c < 4; ++c) a[t][c] = fmaf(v2, u2[c], a[t][c]);
                    #pragma unroll
                    for (int c = 0; c < 4; ++c) a[t][c] = fmaf(v3, u3[c], a[t][c]);
                }
                for (; j < je; j += 2) {
                    u32 e0 = (j + h < je) ? ent[j + h] : 0u;
                    v4f u0 = *(const v4f*)(t32 + (((size_t)(e0 >> 15)) << 7) + (m << 2));
                    float v0 = bfv(e0);
                    #pragma unroll
                    for (int c = 0; c < 4; ++c) a[t][c] = fmaf(v0, u0[c], a[t][c]);
                }
            } else {
                for (; j + 16 <= je; j += 16) {
                    u32 ee[8];
                    #pragma unroll
                    for (int p = 0; p < 8; ++p) ee[p] = ent[j + 2 * p + h];
                    uint2 uu[8];
                    #pragma unroll
                    for (int p = 0; p < 8; ++p)
                        uu[p] = *(const uint2*)(t16 + (((size_t)(ee[p] >> 15)) << 7) + (m << 2));
                    #pragma unroll
                    for (int p = 0; p < 8; ++p) {
                        float v0 = bfv(ee[p]);
                        a[t][0] = fmaf(v0, bf_lo(uu[p].x), a[t][0]);
                        a[t][1] = fmaf(v0, bf_hi(uu[p].x), a[t][1]);
                        a[t][2] = fmaf(v0, bf_lo(uu[p].y), a[t][2]);
                        a[t][3] = fmaf(v0, bf_hi(uu[p].y), a[t][3]);
                    }
                }
                for (; j + 8 <= je; j += 8) {
                    u32 e0 = ent[j + h], e1 = ent[j + 2 + h];
                    u32 e2 = ent[j + 4 + h], e3 = ent[j + 6 + h];
                    uint2 u0 = *(const uint2*)(t16 + (((size_t)(e0 >> 15)) << 7) + (m << 2));
                    uint2 u1 = *(const uint2*)(t16 + (((size_t)(e1 >> 15)) << 7) + (m << 2));
                    uint2 u2 = *(const uint2*)(t16 + (((size_t)(e2 >> 15)) << 7) + (m << 2));
                    uint2 u3 = *(const uint2*)(t16 + (((size_t)(e3 >> 15)) << 7) + (m << 2));
                    float v0 = bfv(e0), v1 = bfv(e1), v2 = bfv(e2), v3 = bfv(e3);
                    a[t][0] = fmaf(v0, bf_lo(u0.x), a[t][0]);
                    a[t][1] = fmaf(v0, bf_hi(u0.x), a[t][1]);
                    a[t][2] = fmaf(v0, bf_lo(u0.y), a[t][2]);
                    a[t][3] = fmaf(v0, bf_hi(u0.y), a[t][3]);
                    a[t][0] = fmaf(v1, bf_lo(u1.x), a[t][0]);
                    a[t][1] = fmaf(v1, bf_hi(u1.x), a[t][1]);
                    a[t][2] = fmaf(v1, bf_lo(u1.y), a[t][2]);
                    a[t][3] = fmaf(v1, bf_hi(u1.y), a[t][3]);
                    a[t][0] = fmaf(v2, bf_lo(u2.x), a[t][0]);
                    a[t][1] = fmaf(v2, bf_hi(u2.x), a[t][1]);
                    a[t][2] = fmaf(v2, bf_lo(u2.y), a[t][2]);
                    a[t][3] = fmaf(v2, bf_hi(u2.y), a[t][3]);
                    a[t][0] = fmaf(v3, bf_lo(u3.x), a[t][0]);
                    a[t][1] = fmaf(v3, bf_hi(u3.x), a[t][1]);
                    a[t][2] = fmaf(v3, bf_lo(u3.y), a[t][2]);
                    a[t][3] = fmaf(v3, bf_hi(u3.y), a[t][3]);
                }
                for (; j < je; j += 2) {
                    u32 e0 = (j + h < je) ? ent[j + h] : 0u;
                    uint2 u0 = *(const uint2*)(t16 + (((size_t)(e0 >> 15)) << 7) + (m << 2));
                    float v0 = bfv(e0);
                    a[t][0] = fmaf(v0, bf_lo(u0.x), a[t][0]);
                    a[t][1] = fmaf(v0, bf_hi(u0.x), a[t][1]);
                    a[t][2] = fmaf(v0, bf_lo(u0.y), a[t][2]);
                    a[t][3] = fmaf(v0, bf_hi(u0.y), a[t][3]);
                }
            }
        }
        __syncthreads();
    }
    int nr = min(64, nrows - r0);
    #pragma unroll
    for (int t = 0; t < 8; ++t) {
        // merge the two half-wave partial sums (entries were split even/odd across halves)
        #pragma unroll
        for (int c = 0; c < 4; ++c) a[t][c] += __shfl_xor(a[t][c], 32);
        int l = wv * 8 + t;
        if (l < nr && h == 0) {
            if (out_fp32) {
                v4f o = {a[t][0], a[t][1], a[t][2], a[t][3]};
                *(v4f*)((float*)out + (((size_t)(r0 + l)) << 7) + (m << 2)) = o;
            } else {
                uint2 ov;
                ov.x = (u32)f2bf(a[t][0]) | ((u32)f2bf(a[t][1]) << 16);
                ov.y = (u32)f2bf(a[t][2]) | ((u32)f2bf(a[t][3]) << 16);
                *(uint2*)((unsigned short*)out + (((size_t)(r0 + l)) << 7) + (m << 2)) = ov;
            }
        }
    }
}

// ---------------- weight prep: Wc = [Wp@Wf_top ; We@Wf_bot], B-fragment packed ----------------
__global__ __launch_bounds__(128) void k_wprep(const float* __restrict__ Wp,
                                               const float* __restrict__ We,
                                               const float* __restrict__ Wf,
                                               unsigned short* __restrict__ wc) {
    int k = blockIdx.x;    // 0..255
    int n = threadIdx.x;   // 0..127
    const float* wrow = (k < 128) ? (Wp + (size_t)k * EMB) : (We + (size_t)(k - 128) * EMB);
    float acc = 0.f;
    #pragma unroll 4
    for (int j = 0; j < EMB; ++j)
        acc = fmaf(wrow[j], Wf[(size_t)((k < 128) ? j : (128 + j)) * EMB + n], acc);
    wc[(((k >> 3) * EMB) + n) * 8 + (k & 7)] = f2bf(acc);
}

// ---------------- fused GEMM (MFMA 16x16x32 bf16): M=nrows, K=256, N=128 ----------------
__global__ __launch_bounds__(256) void k_fused(const unsigned short* __restrict__ poi_agg,
                                               const float* __restrict__ edge,
                                               const unsigned short* __restrict__ wc,
                                               float* __restrict__ fused32,
                                               unsigned short* __restrict__ fused16, int nrows) {
    __shared__ __align__(16) unsigned short lds_w[32768];   // 64 KB packed B
    {
        const uint4* s = (const uint4*)wc;
        uint4* d = (uint4*)lds_w;
        #pragma unroll
        for (int i = 0; i < 16; ++i) d[threadIdx.x + i * 256] = s[threadIdx.x + i * 256];
    }
    __syncthreads();
    int lane = threadIdx.x & 63;
    int row_base = blockIdx.x * 64 + (threadIdx.x >> 6) * 16;
    int m = lane & 15, kq = lane >> 4;
    int arow = row_base + m;
    if (arow >= nrows) arow = nrows - 1;
    const unsigned short* ap_p = poi_agg + (size_t)arow * EMB;
    const float* ap_e = edge + (size_t)arow * EMB;
    v4f zero = {0.f, 0.f, 0.f, 0.f};
    v4f acc[8];
    #pragma unroll
    for (int t = 0; t < 8; ++t) acc[t] = zero;
    #pragma unroll
    for (int kt = 0; kt < 8; ++kt) {
        v8s a;
        if (kt < 4) {
            a = *(const v8s*)(ap_p + kt * 32 + kq * 8);
        } else {
            int k0 = (kt - 4) * 32 + kq * 8;
            v4f f0 = *(const v4f*)(ap_e + k0);
            v4f f1 = *(const v4f*)(ap_e + k0 + 4);
            a[0] = (short)f2bf(f0.x); a[1] = (short)f2bf(f0.y);
            a[2] = (short)f2bf(f0.z); a[3] = (short)f2bf(f0.w);
            a[4] = (short)f2bf(f1.x); a[5] = (short)f2bf(f1.y);
            a[6] = (short)f2bf(f1.z); a[7] = (short)f2bf(f1.w);
        }
        int kk = kt * 4 + kq;
        #pragma unroll
        for (int nt = 0; nt < 8; ++nt) {
            v8s bfr = *(const v8s*)(lds_w + ((kk * EMB + nt * 16 + m) << 3));
            acc[nt] = __builtin_amdgcn_mfma_f32_16x16x32_bf16(a, bfr, acc[nt], 0, 0, 0);
        }
    }
    #pragma unroll
    for (int r = 0; r < 4; ++r) {
        int ro = row_base + kq * 4 + r;
        if (ro >= nrows) continue;
        #pragma unroll
        for (int nt = 0; nt < 8; ++nt) {
            float x = acc[nt][r];
            size_t o = (size_t)ro * EMB + nt * 16 + m;
            fused32[o] = x;
            if (fused16) fused16[o] = f2bf(x);
        }
    }
}

extern "C" void kernel_launch(void* const* d_in, const int* in_sizes, int n_in,
                              void* d_out, int out_size, void* d_ws, size_t ws_size,
                              hipStream_t stream) {
    const float* poi  = (const float*)d_in[0];
    const float* edge = (const float*)d_in[1];
    const int* pte_rows = (const int*)d_in[2];
    const int* pte_cols = (const int*)d_in[3];
    const float* pte_vals = (const float*)d_in[4];
    const int* etp_rows = (const int*)d_in[5];
    const int* etp_cols = (const int*)d_in[6];
    const float* etp_vals = (const float*)d_in[7];
    const float* Wp = (const float*)d_in[8];
    const float* We = (const float*)d_in[9];
    const float* Wf = (const float*)d_in[10];

    int n_poi  = in_sizes[0] / EMB;   // 100000
    int n_edge = in_sizes[1] / EMB;   // 50000
    int nnz1 = in_sizes[2];           // 3.2M
    int nnz2 = in_sizes[5];           // 3.2M

    char* ws = (char*)d_ws;
    size_t off = 0;
    auto alloc = [&](size_t bytes) -> char* {
        char* p = ws + off;
        off = (off + bytes + 255) & ~(size_t)255;
        return p;
    };
    int* bcnt   = (int*)alloc(NBMAX * 4);
    int* bstart = (int*)alloc(NBMAX * 4);
    int* bcur   = (int*)alloc(NBMAX * 4);
    unsigned short* wc = (unsigned short*)alloc((size_t)2 * EMB * EMB * 2);
    int nnz_max = (nnz1 > nnz2) ? nnz1 : nnz2;
    u64* e64 = (u64*)alloc((size_t)nnz_max * 8);  // reused pte -> etp
    // optional bf16 copy of fused (halves spmm#2 gather bytes) — only if ws allows
    size_t f16_bytes = (size_t)n_edge * EMB * 2;
    unsigned short* fused16 = nullptr;
    if (off + f16_bytes <= ws_size) fused16 = (unsigned short*)alloc(f16_bytes);

    // d_out parking: output-0 region (51.2 MB) holds poi_bf + poi_agg until spmm#2
    float* out_prop  = (float*)d_out;                                   // [n_poi][128] fp32
    float* out_fused = out_prop + (size_t)n_poi * EMB;                  // [n_edge][128] fp32
    unsigned short* poi_bf  = (unsigned short*)d_out;                   // 25.6 MB bf16
    unsigned short* poi_agg = poi_bf + (size_t)n_poi * EMB;             // 12.8 MB bf16

    int nb1 = (n_edge + 63) >> BSHIFT;   // 782
    int nb2 = (n_poi + 63) >> BSHIFT;    // 1563

    auto launch_bin = [&](const int* r, const int* c, const float* v, int n, int nb) {
        int ntiles = (n + TILE - 1) / TILE;
        int grid = ntiles < 512 ? ntiles : 512;
        int nbp = ((nb + 63) / 64) * 64;
        if (nbp <= 832)       k_bin<832><<<grid, BINBLK, 0, stream>>>(r, c, v, n, bcur, e64);
        else if (nbp <= 1600) k_bin<1600><<<grid, BINBLK, 0, stream>>>(r, c, v, n, bcur, e64);
        else                  k_bin<2048><<<grid, BINBLK, 0, stream>>>(r, c, v, n, bcur, e64);
    };

    // ---- pte binning ----
    hipMemsetAsync(bcnt, 0, NBMAX * 4, stream);
    k_bcount<<<256, 256, 0, stream>>>(pte_rows, nnz1, bcnt);
    k_bscan<<<1, 256, 0, stream>>>(bcnt, bstart, bcur);
    launch_bin(pte_rows, pte_cols, pte_vals, nnz1, nb1);

    k_cvt<<<(n_poi * EMB / 4 + 255) / 256, 256, 0, stream>>>(poi, poi_bf, n_poi * EMB / 4);
    k_wprep<<<256, 128, 0, stream>>>(Wp, We, Wf, wc);

    // spmm#1: poi_agg[e] = sum vals * poi[col]  (bf16 table -> bf16 out)
    k_bspmm<<<nb1, 512, 0, stream>>>(e64, bstart, bcnt, poi_bf, poi_agg, n_edge, 0, 0);
    // fused = poi_agg @ (Wp@Wf_top) + edge @ (We@Wf_bot) -> output 1 (fp32) [+ bf16 copy]
    k_fused<<<(n_edge + 63) / 64, 256, 0, stream>>>(poi_agg, edge, wc, out_fused, fused16, n_edge);

    // ---- etp binning (e64 reused after spmm#1 consumed it) ----
    hipMemsetAsync(bcnt, 0, NBMAX * 4, stream);
    k_bcount<<<256, 256, 0, stream>>>(etp_rows, nnz2, bcnt);
    k_bscan<<<1, 256, 0, stream>>>(bcnt, bstart, bcur);
    launch_bin(etp_rows, etp_cols, etp_vals, nnz2, nb2);

    // spmm#2: propagated_poi = spmm(etp, fused) -> output 0 (fp32)
    if (fused16)
        k_bspmm<<<nb2, 512, 0, stream>>>(e64, bstart, bcnt, fused16, out_prop, n_poi, 0, 1);
    else
        k_bspmm<<<nb2, 512, 0, stream>>>(e64, bstart, bcnt, out_fused, out_prop, n_poi, 1, 1);
}